// Round 8
// baseline (10625.385 us; speedup 1.0000x reference)
//
#include <hip/hip_runtime.h>

typedef unsigned int u32;
typedef unsigned short u16;
typedef short bf16x8 __attribute__((ext_vector_type(8)));
typedef float f32x4 __attribute__((ext_vector_type(4)));

#define TLEN 1000
#define BATCH 128
#define IDIM 64
#define HDIM 512

#define NWG 128
#define NTHR 256

// ws byte offsets
#define H0_OFF 0
#define H1_OFF 262144
#define BAR_OFF 524288
#define PX0_OFF 525312
#define PH0_OFF 721920
#define PX1_OFF 2294784
#define PH1_OFF 3867648

__device__ __forceinline__ u16 f2bf(float f) {
  u32 u = __float_as_uint(f);
  u += 0x7fffu + ((u >> 16) & 1u);
  return (u16)(u >> 16);
}
__device__ __forceinline__ float bf2f(u16 h) { return __uint_as_float(((u32)h) << 16); }
__device__ __forceinline__ float sigm(float x) { return 1.0f / (1.0f + __expf(-x)); }
__device__ __forceinline__ float tanhfast(float x) {
  float e = __expf(-2.0f * fabsf(x));
  float t = (1.0f - e) / (1.0f + e);
  return x >= 0.0f ? t : -t;
}
__device__ __forceinline__ u32 umin2(u32 a, u32 b) { return a < b ? a : b; }

// ---- LLC-direct (L1+L2 bypass) ops: h/flag WRITES + flag polls only ----
__device__ __forceinline__ void llc_store16(u16* p, u32 v) {
  asm volatile("global_store_short %0, %1, off sc0 sc1" ::"v"(p), "v"(v) : "memory");
}
__device__ __forceinline__ void llc_store32(u32* p, u32 v) {
  asm volatile("global_store_dword %0, %1, off sc0 sc1" ::"v"(p), "v"(v) : "memory");
}
__device__ __forceinline__ uint4 llc_load128(const u32* p) {
  uint4 v;
  asm volatile("global_load_dwordx4 %0, %1, off sc0 sc1\n\ts_waitcnt vmcnt(0)"
               : "=v"(v) : "v"(p) : "memory");
  return v;
}
// per-tick cache invalidate: drop (clean) stale h lines from L1+L2.
// h stores are sc0sc1 write-through, so L1/L2 never hold dirty h lines.
__device__ __forceinline__ void cache_inv() {
  asm volatile("buffer_inv sc0 sc1\n\ts_waitcnt vmcnt(0)" ::: "memory");
}

// ---------------- weight pre-pack into MFMA B-fragment order ----------------
__global__ void pack_weights(const float* Wih0, const float* Whh0,
                             const float* Wih1, const float* Whh1, char* ws) {
  int fid = blockIdx.x * NTHR + threadIdx.x;
  const float* src;
  int K, Kks;
  size_t obase;
  int f = fid;
  if (f < 12288) {
    src = Wih0; K = 64; Kks = 2; obase = PX0_OFF;
  } else if (f < 12288 + 98304) {
    f -= 12288; src = Whh0; K = 512; Kks = 16; obase = PH0_OFF;
  } else if (f < 12288 + 2 * 98304) {
    f -= 12288 + 98304; src = Wih1; K = 512; Kks = 16; obase = PX1_OFF;
  } else if (f < 12288 + 3 * 98304) {
    f -= 12288 + 2 * 98304; src = Whh1; K = 512; Kks = 16; obase = PH1_OFF;
  } else {
    return;
  }
  int lane = f & 63;
  int r = f >> 6;
  int ks = r % Kks; r /= Kks;
  int ct = r % 3;
  int sl = r / 3;
  int grow = ct * 512 + sl * 16 + (lane & 15);
  int k = ks * 32 + ((lane >> 4) * 8);
  const float* s = src + (size_t)grow * K + k;
  u32 p0 = f2bf(s[0]) | ((u32)f2bf(s[1]) << 16);
  u32 p1 = f2bf(s[2]) | ((u32)f2bf(s[3]) << 16);
  u32 p2 = f2bf(s[4]) | ((u32)f2bf(s[5]) << 16);
  u32 p3 = f2bf(s[6]) | ((u32)f2bf(s[7]) << 16);
  *(uint4*)(ws + obase + (size_t)f * 16) = make_uint4(p0, p1, p2, p3);
}

// ---- barrier: 64 monotonic flags/group; release = vmcnt drain + LLC flag store;
//      poll = wave-0 only, 16 lanes x dwordx4 (coalesced), min-reduce ----
__device__ __forceinline__ void fast_barrier(u32* flags, int fidx, u32 target) {
  __syncthreads();  // all waves done (compiler drains vmcnt before barrier)
  if (threadIdx.x == 0) {
    asm volatile("s_waitcnt vmcnt(0)" ::: "memory");
    llc_store32(flags + fidx, target);
  }
  if (threadIdx.x < 64) {
    const int lane = threadIdx.x;
    for (;;) {
      u32 m = 0xFFFFFFFFu;
      if (lane < 16) {
        uint4 v = llc_load128(flags + lane * 4);
        m = umin2(umin2(v.x, v.y), umin2(v.z, v.w));
      }
      m = umin2(m, __shfl_xor(m, 1));
      m = umin2(m, __shfl_xor(m, 2));
      m = umin2(m, __shfl_xor(m, 4));
      m = umin2(m, __shfl_xor(m, 8));
      if (__shfl(m, 0) >= target) break;
      __builtin_amdgcn_s_sleep(2);
    }
  }
  __syncthreads();
}

struct KP {
  const float *x, *bih0, *bhh0, *bih1, *bhh1, *Wfc, *bfc;
  float* out;
  char* ws;
};

#define MFMA(A, B, C) __builtin_amdgcn_mfma_f32_16x16x32_bf16((A), (B), (C), 0, 0, 0)

// single K=512 GEMM, A-frags via CACHED loads (post-inv, L2-shared across WGs)
__device__ __forceinline__ void gemm_cached(const u16* src, const bf16x8 B[3][4], int w,
                                            int lane, f32x4 a0[4], f32x4 a1[4], f32x4 a2[4]) {
  bf16x8 A[4][4];
#pragma unroll
  for (int j = 0; j < 4; ++j)
#pragma unroll
    for (int rt = 0; rt < 4; ++rt)
      A[j][rt] = *(const bf16x8*)(src + (size_t)(rt * 16 + (lane & 15)) * HDIM +
                                  (j * 4 + w) * 32 + ((lane >> 4) * 8));
#pragma unroll
  for (int j = 0; j < 4; ++j)
#pragma unroll
    for (int rt = 0; rt < 4; ++rt) {
      a0[rt] = MFMA(A[j][rt], B[0][j], a0[rt]);
      a1[rt] = MFMA(A[j][rt], B[1][j], a1[rt]);
      a2[rt] = MFMA(A[j][rt], B[2][j], a2[rt]);
    }
}

// two K=512 GEMMs, merged load batch (cached)
__device__ __forceinline__ void gemm_pair(const u16* s1, const u16* s2,
                                          const bf16x8 B1[3][4], const bf16x8 B2[3][4],
                                          int w, int lane, f32x4 aR[4], f32x4 aZ[4],
                                          f32x4 aXN[4], f32x4 aHN[4]) {
  bf16x8 A1[4][4], A2[4][4];
#pragma unroll
  for (int j = 0; j < 4; ++j)
#pragma unroll
    for (int rt = 0; rt < 4; ++rt) {
      A1[j][rt] = *(const bf16x8*)(s1 + (size_t)(rt * 16 + (lane & 15)) * HDIM +
                                   (j * 4 + w) * 32 + ((lane >> 4) * 8));
      A2[j][rt] = *(const bf16x8*)(s2 + (size_t)(rt * 16 + (lane & 15)) * HDIM +
                                   (j * 4 + w) * 32 + ((lane >> 4) * 8));
    }
#pragma unroll
  for (int j = 0; j < 4; ++j)
#pragma unroll
    for (int rt = 0; rt < 4; ++rt) {
      aR[rt] = MFMA(A1[j][rt], B1[0][j], aR[rt]);
      aZ[rt] = MFMA(A1[j][rt], B1[1][j], aZ[rt]);
      aXN[rt] = MFMA(A1[j][rt], B1[2][j], aXN[rt]);
    }
#pragma unroll
  for (int j = 0; j < 4; ++j)
#pragma unroll
    for (int rt = 0; rt < 4; ++rt) {
      aR[rt] = MFMA(A2[j][rt], B2[0][j], aR[rt]);
      aZ[rt] = MFMA(A2[j][rt], B2[1][j], aZ[rt]);
      aHN[rt] = MFMA(A2[j][rt], B2[2][j], aHN[rt]);
    }
}

__global__ __launch_bounds__(NTHR, 1) void gru_main(KP P) {
  __shared__ f32x4 red[8][4][64];  // 32 KB cross-wave reduce (2-pass)
  const int tid = threadIdx.x;
  const int lane = tid & 63;
  const int w = tid >> 6;  // K-quarter (ksteps == w mod 4)
  // XCD-aware decode: XCD = blockIdx.x % 8; (bg,layer) pinned to an XCD pair so
  // each XCD's L2 re-fetches only its own slab(s) after the per-tick inv.
  const int b = blockIdx.x;
  const int bg = (b >> 2) & 1;
  const int layer = (b >> 1) & 1;
  const int sl = ((b & 1) | ((b >> 3) << 1)) & 31;

  char* ws = P.ws;
  u16* h0 = (u16*)(ws + H0_OFF);
  u16* h1 = (u16*)(ws + H1_OFF);
  u32* flags = (u32*)(ws + BAR_OFF) + bg * 64;
  const int fidx = layer * 32 + sl;
  const bf16x8* px = (const bf16x8*)(ws + (layer ? PX1_OFF : PX0_OFF));
  const bf16x8* ph = (const bf16x8*)(ws + (layer ? PH1_OFF : PH0_OFF));

  const float* bih = layer ? P.bih1 : P.bih0;
  const float* bhh = layer ? P.bhh1 : P.bhh0;
  const int jj = sl * 16 + (lane & 15);
  const float b_r = bih[jj] + bhh[jj];
  const float b_z = bih[HDIM + jj] + bhh[HDIM + jj];
  const float b_nx = bih[2 * HDIM + jj];
  const float b_nh = bhh[2 * HDIM + jj];

  u16* hout = layer ? h1 : h0;
  const size_t bgoff = (size_t)bg * 64 * HDIM;

  // ---- persistent B fragments in registers: kstep = j*4 + w ----
  bf16x8 xB[3][4], hB[3][4];
#pragma unroll
  for (int ct = 0; ct < 3; ++ct)
#pragma unroll
    for (int j = 0; j < 4; ++j)
      hB[ct][j] = ph[((size_t)(sl * 3 + ct) * 16 + (j * 4 + w)) * 64 + lane];
  if (layer == 0) {
    const bf16x8 z8 = {0, 0, 0, 0, 0, 0, 0, 0};
#pragma unroll
    for (int ct = 0; ct < 3; ++ct)
#pragma unroll
      for (int j = 0; j < 4; ++j) xB[ct][j] = z8;
    if (w < 2) {
#pragma unroll
      for (int ct = 0; ct < 3; ++ct)
        xB[ct][0] = px[((size_t)(sl * 3 + ct) * 2 + w) * 64 + lane];
    }
  } else {
#pragma unroll
    for (int ct = 0; ct < 3; ++ct)
#pragma unroll
      for (int j = 0; j < 4; ++j)
        xB[ct][j] = px[((size_t)(sl * 3 + ct) * 16 + (j * 4 + w)) * 64 + lane];
  }

  const f32x4 zf = {0.f, 0.f, 0.f, 0.f};
  f32x4 hown = zf;

#pragma unroll 1
  for (int tick = 0; tick <= TLEN; ++tick) {
    const int p = tick & 1;
    const bool active = (layer == 0) ? (tick < TLEN) : (tick >= 1);
    if (active) {
      cache_inv();  // drop stale (clean) h lines; fresh data comes from LLC
      f32x4 aR[4], aZ[4], aXN[4], aHN[4];
#pragma unroll
      for (int rt = 0; rt < 4; ++rt) { aR[rt] = zf; aZ[rt] = zf; aXN[rt] = zf; aHN[rt] = zf; }
      const u16* h0src = h0 + (size_t)(1 - p) * BATCH * HDIM + bgoff;

      if (layer == 0) {
        if (w < 2) {
#pragma unroll
          for (int rt = 0; rt < 4; ++rt) {
            const float* s = P.x +
                ((size_t)(bg * 64 + rt * 16 + (lane & 15)) * TLEN + tick) * IDIM +
                w * 32 + ((lane >> 4) * 8);
            float4 v0 = ((const float4*)s)[0];
            float4 v1 = ((const float4*)s)[1];
            bf16x8 A;
            A[0] = (short)f2bf(v0.x); A[1] = (short)f2bf(v0.y);
            A[2] = (short)f2bf(v0.z); A[3] = (short)f2bf(v0.w);
            A[4] = (short)f2bf(v1.x); A[5] = (short)f2bf(v1.y);
            A[6] = (short)f2bf(v1.z); A[7] = (short)f2bf(v1.w);
            aR[rt] = MFMA(A, xB[0][0], aR[rt]);
            aZ[rt] = MFMA(A, xB[1][0], aZ[rt]);
            aXN[rt] = MFMA(A, xB[2][0], aXN[rt]);
          }
        }
        gemm_cached(h0src, hB, w, lane, aR, aZ, aHN);
      } else {
        const u16* h1src = h1 + (size_t)(1 - p) * BATCH * HDIM + bgoff;
        gemm_pair(h0src, h1src, xB, hB, w, lane, aR, aZ, aXN, aHN);
      }

      // ---- cross-wave K reduction, 2 passes of 32 KB ----
#pragma unroll
      for (int rt = 0; rt < 4; ++rt) {
        red[w * 2 + 0][rt][lane] = aR[rt];
        red[w * 2 + 1][rt][lane] = aZ[rt];
      }
      __syncthreads();
      f32x4 R = zf, Z = zf, XN = zf, HN = zf;
#pragma unroll
      for (int kq = 0; kq < 4; ++kq) {
        R = R + red[kq * 2 + 0][w][lane];
        Z = Z + red[kq * 2 + 1][w][lane];
      }
      __syncthreads();
#pragma unroll
      for (int rt = 0; rt < 4; ++rt) {
        red[w * 2 + 0][rt][lane] = aXN[rt];
        red[w * 2 + 1][rt][lane] = aHN[rt];
      }
      __syncthreads();
#pragma unroll
      for (int kq = 0; kq < 4; ++kq) {
        XN = XN + red[kq * 2 + 0][w][lane];
        HN = HN + red[kq * 2 + 1][w][lane];
      }

      // ---- gates + state update + LLC-direct h store (wave w owns row-tile w) ----
      u16* hw = hout + (size_t)p * BATCH * HDIM;
#pragma unroll
      for (int q = 0; q < 4; ++q) {
        float r = sigm(R[q] + b_r);
        float z = sigm(Z[q] + b_z);
        float n = tanhfast(XN[q] + b_nx + r * (HN[q] + b_nh));
        float hv = (1.f - z) * n + z * hown[q];
        hown[q] = hv;
        int rowb = bg * 64 + w * 16 + (lane >> 4) * 4 + q;
        llc_store16(&hw[(size_t)rowb * HDIM + jj], (u32)f2bf(hv));
      }
    }
    fast_barrier(flags, fidx, (u32)(tick + 1));
  }

  // ---- final FC + sigmoid: hT1 = h1[parity 0] ----
  if (layer == 1 && sl == 0) {
    cache_inv();  // L2 holds stale parity-0 h1 lines from tick-999 reads
    const u16* hT = h1;  // p=0 holds t=999
    int b2 = tid >> 2, qq = tid & 3;
    const u16* hr = hT + (size_t)(bg * 64 + b2) * HDIM + qq * 128;
    const float* wf = P.Wfc + qq * 128;
    float s = 0.f;
#pragma unroll 4
    for (int k = 0; k < 128; ++k) s += bf2f(hr[k]) * wf[k];
    s += __shfl_xor(s, 1);
    s += __shfl_xor(s, 2);
    if (qq == 0) P.out[bg * 64 + b2] = sigm(s + P.bfc[0]);
  }
}

extern "C" void kernel_launch(void* const* d_in, const int* in_sizes, int n_in,
                              void* d_out, int out_size, void* d_ws, size_t ws_size,
                              hipStream_t stream) {
  const float* x = (const float*)d_in[0];
  const float* Wih0 = (const float*)d_in[1];
  const float* Whh0 = (const float*)d_in[2];
  const float* bih0 = (const float*)d_in[3];
  const float* bhh0 = (const float*)d_in[4];
  const float* Wih1 = (const float*)d_in[5];
  const float* Whh1 = (const float*)d_in[6];
  const float* bih1 = (const float*)d_in[7];
  const float* bhh1 = (const float*)d_in[8];
  const float* Wfc = (const float*)d_in[9];
  const float* bfc = (const float*)d_in[10];

  hipMemsetAsync(d_ws, 0, BAR_OFF + 1024, stream);
  pack_weights<<<dim3(1200), dim3(NTHR), 0, stream>>>(Wih0, Whh0, Wih1, Whh1, (char*)d_ws);

  KP P = {x, bih0, bhh0, bih1, bhh1, Wfc, bfc, (float*)d_out, (char*)d_ws};
  void* args[] = {&P};
  hipError_t ce = hipLaunchCooperativeKernel((void*)gru_main, dim3(NWG), dim3(NTHR), args, 0,
                                             stream);
  if (ce != hipSuccess) {
    // co-residency trivially satisfied (128 WGs on 256 CUs, 32 KB LDS, 1 WG/CU);
    // the inter-WG barrier is hand-rolled flags, so a plain launch is safe.
    (void)hipGetLastError();  // clear error state
    gru_main<<<dim3(NWG), dim3(NTHR), 0, stream>>>(P);
  }
}

// Round 9
// 5253.823 us; speedup vs baseline: 2.0224x; 2.0224x over previous
//
#include <hip/hip_runtime.h>

typedef unsigned int u32;
typedef unsigned short u16;
typedef short bf16x8 __attribute__((ext_vector_type(8)));
typedef float f32x4 __attribute__((ext_vector_type(4)));

#define TLEN 1000
#define BATCH 128
#define IDIM 64
#define HDIM 512

#define NWG 128
#define NTHR 256

// ws byte offsets
#define H0_OFF 0
#define H1_OFF 262144
#define BAR_OFF 524288
#define PX0_OFF 525312
#define PH0_OFF 721920
#define PX1_OFF 2294784
#define PH1_OFF 3867648

__device__ __forceinline__ u16 f2bf(float f) {
  u32 u = __float_as_uint(f);
  u += 0x7fffu + ((u >> 16) & 1u);
  return (u16)(u >> 16);
}
__device__ __forceinline__ float bf2f(u16 h) { return __uint_as_float(((u32)h) << 16); }
__device__ __forceinline__ float sigm(float x) { return 1.0f / (1.0f + __expf(-x)); }
__device__ __forceinline__ float tanhfast(float x) {
  float e = __expf(-2.0f * fabsf(x));
  float t = (1.0f - e) / (1.0f + e);
  return x >= 0.0f ? t : -t;
}
__device__ __forceinline__ u32 umin2(u32 a, u32 b) { return a < b ? a : b; }

// ---- LLC-direct (L1+L2 bypass) ops: all cross-WG-visible traffic ----
__device__ __forceinline__ void llc_store16(u16* p, u32 v) {
  asm volatile("global_store_short %0, %1, off sc0 sc1" ::"v"(p), "v"(v) : "memory");
}
__device__ __forceinline__ void llc_store32(u32* p, u32 v) {
  asm volatile("global_store_dword %0, %1, off sc0 sc1" ::"v"(p), "v"(v) : "memory");
}
__device__ __forceinline__ uint4 llc_load128(const u32* p) {
  uint4 v;
  asm volatile("global_load_dwordx4 %0, %1, off sc0 sc1\n\ts_waitcnt vmcnt(0)"
               : "=v"(v) : "v"(p) : "memory");
  return v;
}
#define LLC_LOAD16(dst, p) \
  asm volatile("global_load_dwordx4 %0, %1, off sc0 sc1" : "=v"(dst) : "v"(p))

// ---------------- weight pre-pack into MFMA B-fragment order (unchanged) ------
__global__ void pack_weights(const float* Wih0, const float* Whh0,
                             const float* Wih1, const float* Whh1, char* ws) {
  int fid = blockIdx.x * NTHR + threadIdx.x;
  const float* src;
  int K, Kks;
  size_t obase;
  int f = fid;
  if (f < 12288) {
    src = Wih0; K = 64; Kks = 2; obase = PX0_OFF;
  } else if (f < 12288 + 98304) {
    f -= 12288; src = Whh0; K = 512; Kks = 16; obase = PH0_OFF;
  } else if (f < 12288 + 2 * 98304) {
    f -= 12288 + 98304; src = Wih1; K = 512; Kks = 16; obase = PX1_OFF;
  } else if (f < 12288 + 3 * 98304) {
    f -= 12288 + 2 * 98304; src = Whh1; K = 512; Kks = 16; obase = PH1_OFF;
  } else {
    return;
  }
  int lane = f & 63;
  int r = f >> 6;
  int ks = r % Kks; r /= Kks;
  int ct = r % 3;
  int sl = r / 3;
  int grow = ct * 512 + sl * 16 + (lane & 15);
  int k = ks * 32 + ((lane >> 4) * 8);
  const float* s = src + (size_t)grow * K + k;
  u32 p0 = f2bf(s[0]) | ((u32)f2bf(s[1]) << 16);
  u32 p1 = f2bf(s[2]) | ((u32)f2bf(s[3]) << 16);
  u32 p2 = f2bf(s[4]) | ((u32)f2bf(s[5]) << 16);
  u32 p3 = f2bf(s[6]) | ((u32)f2bf(s[7]) << 16);
  *(uint4*)(ws + obase + (size_t)f * 16) = make_uint4(p0, p1, p2, p3);
}

// ---- barrier: 32 monotonic flags per batch-group; poll = 8 lanes x dwordx4 ----
__device__ __forceinline__ void fast_barrier(u32* flags, int fidx, u32 target) {
  __syncthreads();
  if (threadIdx.x == 0) {
    asm volatile("s_waitcnt vmcnt(0)" ::: "memory");
    llc_store32(flags + fidx, target);
  }
  if (threadIdx.x < 64) {
    const int lane = threadIdx.x;
    for (;;) {
      u32 m = 0xFFFFFFFFu;
      if (lane < 8) {
        uint4 v = llc_load128(flags + lane * 4);
        m = umin2(umin2(v.x, v.y), umin2(v.z, v.w));
      }
      m = umin2(m, __shfl_xor(m, 1));
      m = umin2(m, __shfl_xor(m, 2));
      m = umin2(m, __shfl_xor(m, 4));
      if (__shfl(m, 0) >= target) break;
      __builtin_amdgcn_s_sleep(2);
    }
  }
  __syncthreads();
}

struct KP {
  const float *x, *bih0, *bhh0, *bih1, *bhh1, *Wfc, *bfc;
  float* out;
  char* ws;
};

#define MFMA(A, B, C) __builtin_amdgcn_mfma_f32_16x16x32_bf16((A), (B), (C), 0, 0, 0)

__global__ __launch_bounds__(NTHR, 1) void gru_main(KP P) {
  __shared__ f32x4 red[4][8][64];  // 32 KB cross-wave reduce (2-pass)
  const int tid = threadIdx.x;
  const int lane = tid & 63;
  const int w = tid >> 6;          // K-quarter (ksteps == w mod 4)
  const int rtw = w >> 1;          // this wave's output row-tile after reduce
  const int csw = w & 1;           // this wave's output col-slice after reduce
  const int b = blockIdx.x;
  const int layer = b & 1;
  const int bg = (b >> 1) & 3;     // 4 batch groups x 32 rows
  const int colWG = b >> 3;        // 16 col groups x 32 cols

  char* ws = P.ws;
  u16* h0 = (u16*)(ws + H0_OFF);
  u16* h1 = (u16*)(ws + H1_OFF);
  u32* flags = (u32*)(ws + BAR_OFF) + bg * 64;  // 32 used, 256B spacing
  const int fidx = layer * 16 + colWG;
  const bf16x8* px = (const bf16x8*)(ws + (layer ? PX1_OFF : PX0_OFF));
  const bf16x8* ph = (const bf16x8*)(ws + (layer ? PH1_OFF : PH0_OFF));

  const float* bih = layer ? P.bih1 : P.bih0;
  const float* bhh = layer ? P.bhh1 : P.bhh0;
  const int jj = colWG * 32 + csw * 16 + (lane & 15);  // this thread's output col
  const float b_r = bih[jj] + bhh[jj];
  const float b_z = bih[HDIM + jj] + bhh[HDIM + jj];
  const float b_nx = bih[2 * HDIM + jj];
  const float b_nh = bhh[2 * HDIM + jj];

  u16* hout = layer ? h1 : h0;
  const size_t bgoff = (size_t)bg * 32 * HDIM;

  // ---- persistent B fragments: col-slices sl = colWG*2 + cs; kstep = j*4 + w ----
  bf16x8 xB[3][2][4], hB[3][2][4];
#pragma unroll
  for (int ct = 0; ct < 3; ++ct)
#pragma unroll
    for (int cs = 0; cs < 2; ++cs)
#pragma unroll
      for (int j = 0; j < 4; ++j)
        hB[ct][cs][j] =
            ph[((size_t)((colWG * 2 + cs) * 3 + ct) * 16 + (j * 4 + w)) * 64 + lane];
  if (layer == 0) {
    const bf16x8 z8 = {0, 0, 0, 0, 0, 0, 0, 0};
#pragma unroll
    for (int ct = 0; ct < 3; ++ct)
#pragma unroll
      for (int cs = 0; cs < 2; ++cs)
#pragma unroll
        for (int j = 0; j < 4; ++j) xB[ct][cs][j] = z8;
    if (w < 2) {
#pragma unroll
      for (int ct = 0; ct < 3; ++ct)
#pragma unroll
        for (int cs = 0; cs < 2; ++cs)
          xB[ct][cs][0] = px[((size_t)((colWG * 2 + cs) * 3 + ct) * 2 + w) * 64 + lane];
    }
  } else {
#pragma unroll
    for (int ct = 0; ct < 3; ++ct)
#pragma unroll
      for (int cs = 0; cs < 2; ++cs)
#pragma unroll
        for (int j = 0; j < 4; ++j)
          xB[ct][cs][j] =
              px[((size_t)((colWG * 2 + cs) * 3 + ct) * 16 + (j * 4 + w)) * 64 + lane];
  }

  const f32x4 zf = {0.f, 0.f, 0.f, 0.f};
  f32x4 hown = zf;

#pragma unroll 1
  for (int tick = 0; tick <= TLEN; ++tick) {
    const int p = tick & 1;
    const bool active = (layer == 0) ? (tick < TLEN) : (tick >= 1);
    if (active) {
      f32x4 aR[2][2], aZ[2][2], aXN[2][2], aHN[2][2];
#pragma unroll
      for (int rt = 0; rt < 2; ++rt)
#pragma unroll
        for (int cs = 0; cs < 2; ++cs) {
          aR[rt][cs] = zf; aZ[rt][cs] = zf; aXN[rt][cs] = zf; aHN[rt][cs] = zf;
        }
      const u16* h0src = h0 + (size_t)(1 - p) * BATCH * HDIM + bgoff;

      if (layer == 0) {
        // x-gemm (K=64: waves 0,1 own kstep w) from cached fp32 x
        if (w < 2) {
#pragma unroll
          for (int rt = 0; rt < 2; ++rt) {
            const float* s = P.x +
                ((size_t)(bg * 32 + rt * 16 + (lane & 15)) * TLEN + tick) * IDIM +
                w * 32 + ((lane >> 4) * 8);
            float4 v0 = ((const float4*)s)[0];
            float4 v1 = ((const float4*)s)[1];
            bf16x8 A;
            A[0] = (short)f2bf(v0.x); A[1] = (short)f2bf(v0.y);
            A[2] = (short)f2bf(v0.z); A[3] = (short)f2bf(v0.w);
            A[4] = (short)f2bf(v1.x); A[5] = (short)f2bf(v1.y);
            A[6] = (short)f2bf(v1.z); A[7] = (short)f2bf(v1.w);
#pragma unroll
            for (int cs = 0; cs < 2; ++cs) {
              aR[rt][cs] = MFMA(A, xB[0][cs][0], aR[rt][cs]);
              aZ[rt][cs] = MFMA(A, xB[1][cs][0], aZ[rt][cs]);
              aXN[rt][cs] = MFMA(A, xB[2][cs][0], aXN[rt][cs]);
            }
          }
        }
        // h-gemm: 8 LLC loads, one drain, 48 MFMAs
        bf16x8 A[4][2];
#pragma unroll
        for (int j = 0; j < 4; ++j)
#pragma unroll
          for (int rt = 0; rt < 2; ++rt) {
            const u16* pp = h0src + (size_t)(rt * 16 + (lane & 15)) * HDIM +
                            (j * 4 + w) * 32 + ((lane >> 4) * 8);
            LLC_LOAD16(A[j][rt], pp);
          }
        asm volatile("s_waitcnt vmcnt(0)" ::: "memory");
        __builtin_amdgcn_sched_barrier(0);
#pragma unroll
        for (int j = 0; j < 4; ++j)
#pragma unroll
          for (int rt = 0; rt < 2; ++rt)
#pragma unroll
            for (int cs = 0; cs < 2; ++cs) {
              aR[rt][cs] = MFMA(A[j][rt], hB[0][cs][j], aR[rt][cs]);
              aZ[rt][cs] = MFMA(A[j][rt], hB[1][cs][j], aZ[rt][cs]);
              aHN[rt][cs] = MFMA(A[j][rt], hB[2][cs][j], aHN[rt][cs]);
            }
      } else {
        const u16* h1src = h1 + (size_t)(1 - p) * BATCH * HDIM + bgoff;
        // merged pair: 16 LLC loads, one drain, 96 MFMAs
        bf16x8 A1[4][2], A2[4][2];
#pragma unroll
        for (int j = 0; j < 4; ++j)
#pragma unroll
          for (int rt = 0; rt < 2; ++rt) {
            const u16* p1 = h0src + (size_t)(rt * 16 + (lane & 15)) * HDIM +
                            (j * 4 + w) * 32 + ((lane >> 4) * 8);
            const u16* p2 = h1src + (size_t)(rt * 16 + (lane & 15)) * HDIM +
                            (j * 4 + w) * 32 + ((lane >> 4) * 8);
            LLC_LOAD16(A1[j][rt], p1);
            LLC_LOAD16(A2[j][rt], p2);
          }
        asm volatile("s_waitcnt vmcnt(0)" ::: "memory");
        __builtin_amdgcn_sched_barrier(0);
#pragma unroll
        for (int j = 0; j < 4; ++j)
#pragma unroll
          for (int rt = 0; rt < 2; ++rt)
#pragma unroll
            for (int cs = 0; cs < 2; ++cs) {
              aR[rt][cs] = MFMA(A1[j][rt], xB[0][cs][j], aR[rt][cs]);
              aZ[rt][cs] = MFMA(A1[j][rt], xB[1][cs][j], aZ[rt][cs]);
              aXN[rt][cs] = MFMA(A1[j][rt], xB[2][cs][j], aXN[rt][cs]);
            }
#pragma unroll
        for (int j = 0; j < 4; ++j)
#pragma unroll
          for (int rt = 0; rt < 2; ++rt)
#pragma unroll
            for (int cs = 0; cs < 2; ++cs) {
              aR[rt][cs] = MFMA(A2[j][rt], hB[0][cs][j], aR[rt][cs]);
              aZ[rt][cs] = MFMA(A2[j][rt], hB[1][cs][j], aZ[rt][cs]);
              aHN[rt][cs] = MFMA(A2[j][rt], hB[2][cs][j], aHN[rt][cs]);
            }
      }

      // ---- cross-wave K reduction, 2 passes (idx = set*4 + rt*2 + cs) ----
#pragma unroll
      for (int rt = 0; rt < 2; ++rt)
#pragma unroll
        for (int cs = 0; cs < 2; ++cs) {
          red[w][0 + rt * 2 + cs][lane] = aR[rt][cs];
          red[w][4 + rt * 2 + cs][lane] = aZ[rt][cs];
        }
      __syncthreads();
      f32x4 R = zf, Z = zf, XN = zf, HN = zf;
#pragma unroll
      for (int kq = 0; kq < 4; ++kq) {
        R = R + red[kq][0 + rtw * 2 + csw][lane];
        Z = Z + red[kq][4 + rtw * 2 + csw][lane];
      }
      __syncthreads();
#pragma unroll
      for (int rt = 0; rt < 2; ++rt)
#pragma unroll
        for (int cs = 0; cs < 2; ++cs) {
          red[w][0 + rt * 2 + cs][lane] = aXN[rt][cs];
          red[w][4 + rt * 2 + cs][lane] = aHN[rt][cs];
        }
      __syncthreads();
#pragma unroll
      for (int kq = 0; kq < 4; ++kq) {
        XN = XN + red[kq][0 + rtw * 2 + csw][lane];
        HN = HN + red[kq][4 + rtw * 2 + csw][lane];
      }

      // ---- gates + state update + LLC-direct h store ----
      u16* hw = hout + (size_t)p * BATCH * HDIM;
#pragma unroll
      for (int q = 0; q < 4; ++q) {
        float r = sigm(R[q] + b_r);
        float z = sigm(Z[q] + b_z);
        float n = tanhfast(XN[q] + b_nx + r * (HN[q] + b_nh));
        float hv = (1.f - z) * n + z * hown[q];
        hown[q] = hv;
        int rowb = bg * 32 + rtw * 16 + (lane >> 4) * 4 + q;
        llc_store16(&hw[(size_t)rowb * HDIM + jj], (u32)f2bf(hv));
      }
    }
    fast_barrier(flags, fidx, (u32)(tick + 1));
  }

  // ---- final FC + sigmoid: hT1 = h1[parity 0] (h1 lines never in L1/L2) ----
  if (layer == 1 && colWG == 0) {
    const u16* hT = h1;  // p=0 holds t=999
    int row = tid >> 3, qq = tid & 7;
    const u16* hr = hT + (size_t)(bg * 32 + row) * HDIM + qq * 64;
    const float* wf = P.Wfc + qq * 64;
    float s = 0.f;
#pragma unroll 4
    for (int k = 0; k < 64; ++k) s += bf2f(hr[k]) * wf[k];
    s += __shfl_xor(s, 1);
    s += __shfl_xor(s, 2);
    s += __shfl_xor(s, 4);
    if (qq == 0) P.out[bg * 32 + row] = sigm(s + P.bfc[0]);
  }
}

extern "C" void kernel_launch(void* const* d_in, const int* in_sizes, int n_in,
                              void* d_out, int out_size, void* d_ws, size_t ws_size,
                              hipStream_t stream) {
  const float* x = (const float*)d_in[0];
  const float* Wih0 = (const float*)d_in[1];
  const float* Whh0 = (const float*)d_in[2];
  const float* bih0 = (const float*)d_in[3];
  const float* bhh0 = (const float*)d_in[4];
  const float* Wih1 = (const float*)d_in[5];
  const float* Whh1 = (const float*)d_in[6];
  const float* bih1 = (const float*)d_in[7];
  const float* bhh1 = (const float*)d_in[8];
  const float* Wfc = (const float*)d_in[9];
  const float* bfc = (const float*)d_in[10];

  hipMemsetAsync(d_ws, 0, BAR_OFF + 1024, stream);
  pack_weights<<<dim3(1200), dim3(NTHR), 0, stream>>>(Wih0, Whh0, Wih1, Whh1, (char*)d_ws);

  KP P = {x, bih0, bhh0, bih1, bhh1, Wfc, bfc, (float*)d_out, (char*)d_ws};
  void* args[] = {&P};
  hipError_t ce = hipLaunchCooperativeKernel((void*)gru_main, dim3(NWG), dim3(NTHR), args, 0,
                                             stream);
  if (ce != hipSuccess) {
    // co-residency trivially satisfied (128 WGs on 256 CUs, 32 KB LDS, 1 WG/CU);
    // the inter-WG barrier is hand-rolled flags, so a plain launch is safe.
    (void)hipGetLastError();  // clear error state
    gru_main<<<dim3(NWG), dim3(NTHR), 0, stream>>>(P);
  }
}

// Round 11
// 3994.875 us; speedup vs baseline: 2.6598x; 1.3151x over previous
//
#include <hip/hip_runtime.h>

typedef unsigned int u32;
typedef unsigned short u16;
typedef short bf16x8 __attribute__((ext_vector_type(8)));
typedef float f32x4 __attribute__((ext_vector_type(4)));

#define TLEN 1000
#define BATCH 128
#define IDIM 64
#define HDIM 512

#define NWG 256
#define NTHR 256

// ws byte offsets (pack offsets unchanged)
#define H0_OFF 0
#define H1_OFF 262144
#define PX0_OFF 525312
#define PH0_OFF 721920
#define PX1_OFF 2294784
#define PH1_OFF 3867648
#define FLG_OFF 5440512
#define XSL_OFF 5442560

__device__ __forceinline__ u16 f2bf(float f) {
  u32 u = __float_as_uint(f);
  u += 0x7fffu + ((u >> 16) & 1u);
  return (u16)(u >> 16);
}
__device__ __forceinline__ float bf2f(u16 h) { return __uint_as_float(((u32)h) << 16); }
__device__ __forceinline__ float sigm(float x) { return 1.0f / (1.0f + __expf(-x)); }
__device__ __forceinline__ float tanhfast(float x) {
  float e = __expf(-2.0f * fabsf(x));
  float t = (1.0f - e) / (1.0f + e);
  return x >= 0.0f ? t : -t;
}
__device__ __forceinline__ u32 umin2(u32 a, u32 b) { return a < b ? a : b; }
__device__ __forceinline__ u32 umax2(u32 a, u32 b) { return a > b ? a : b; }

// ---- LLC-scope (sc0 sc1) ops: barrier flags + non-local clusters ----
__device__ __forceinline__ void llc_st16(u16* p, u32 v) {
  asm volatile("global_store_short %0, %1, off sc0 sc1" ::"v"(p), "v"(v) : "memory");
}
__device__ __forceinline__ void llc_st32(u32* p, u32 v) {
  asm volatile("global_store_dword %0, %1, off sc0 sc1" ::"v"(p), "v"(v) : "memory");
}
__device__ __forceinline__ uint4 llc_ld128(const u32* p) {
  uint4 v;
  asm volatile("global_load_dwordx4 %0, %1, off sc0 sc1\n\ts_waitcnt vmcnt(0)"
               : "=v"(v) : "v"(p) : "memory");
  return v;
}
__device__ __forceinline__ void llc_ldA(bf16x8& d, const u16* p) {
  asm volatile("global_load_dwordx4 %0, %1, off sc0 sc1" : "=v"(d) : "v"(p));
}
// ---- XCD-local (sc0 only) ops: h data when cluster is verified XCD-local ----
__device__ __forceinline__ void l2_st16(u16* p, u32 v) {
  asm volatile("global_store_short %0, %1, off sc0" ::"v"(p), "v"(v) : "memory");
}
__device__ __forceinline__ void l2_ldA(bf16x8& d, const u16* p) {
  asm volatile("global_load_dwordx4 %0, %1, off sc0" : "=v"(d) : "v"(p));
}

// ---------------- weight pre-pack into MFMA B-fragment order (unchanged) ------
__global__ void pack_weights(const float* Wih0, const float* Whh0,
                             const float* Wih1, const float* Whh1, char* ws) {
  int fid = blockIdx.x * NTHR + threadIdx.x;
  const float* src;
  int K, Kks;
  size_t obase;
  int f = fid;
  if (f < 12288) {
    src = Wih0; K = 64; Kks = 2; obase = PX0_OFF;
  } else if (f < 12288 + 98304) {
    f -= 12288; src = Whh0; K = 512; Kks = 16; obase = PH0_OFF;
  } else if (f < 12288 + 2 * 98304) {
    f -= 12288 + 98304; src = Wih1; K = 512; Kks = 16; obase = PX1_OFF;
  } else if (f < 12288 + 3 * 98304) {
    f -= 12288 + 2 * 98304; src = Whh1; K = 512; Kks = 16; obase = PH1_OFF;
  } else {
    return;
  }
  int lane = f & 63;
  int r = f >> 6;
  int ks = r % Kks; r /= Kks;
  int ct = r % 3;
  int sl = r / 3;
  int grow = ct * 512 + sl * 16 + (lane & 15);
  int k = ks * 32 + ((lane >> 4) * 8);
  const float* s = src + (size_t)grow * K + k;
  u32 p0 = f2bf(s[0]) | ((u32)f2bf(s[1]) << 16);
  u32 p1 = f2bf(s[2]) | ((u32)f2bf(s[3]) << 16);
  u32 p2 = f2bf(s[4]) | ((u32)f2bf(s[5]) << 16);
  u32 p3 = f2bf(s[6]) | ((u32)f2bf(s[7]) << 16);
  *(uint4*)(ws + obase + (size_t)f * 16) = make_uint4(p0, p1, p2, p3);
}

// ---- barrier: ALWAYS sc0 sc1 (proven r6-r9 machinery). 32 flags/cluster. ----
__device__ __forceinline__ void fast_barrier(u32* flags, int fidx, u32 target) {
  __syncthreads();  // compiler drains vmcnt per-wave before s_barrier
  if (threadIdx.x == 0) {
    asm volatile("s_waitcnt vmcnt(0)" ::: "memory");
    llc_st32(flags + fidx, target);
  }
  if (threadIdx.x < 64) {
    const int lane = threadIdx.x;
    for (;;) {
      u32 m = 0xFFFFFFFFu;
      if (lane < 8) {
        uint4 v = llc_ld128(flags + lane * 4);
        m = umin2(umin2(v.x, v.y), umin2(v.z, v.w));
      }
      m = umin2(m, __shfl_xor(m, 1));
      m = umin2(m, __shfl_xor(m, 2));
      m = umin2(m, __shfl_xor(m, 4));
      if (__shfl(m, 0) >= target) break;
      __builtin_amdgcn_s_sleep(2);
    }
  }
  __syncthreads();
}

struct KP {
  const float *x, *bih0, *bhh0, *bih1, *bhh1, *Wfc, *bfc;
  float* out;
  char* ws;
};

#define MFMA(A, B, C) __builtin_amdgcn_mfma_f32_16x16x32_bf16((A), (B), (C), 0, 0, 0)

__global__ __launch_bounds__(NTHR, 1) void gru_main(KP P) {
  __shared__ f32x4 red[4][4][64];  // 16 KB cross-wave reduce (2-pass)
  const int tid = threadIdx.x;
  const int lane = tid & 63;
  const int w = tid >> 6;        // K-quarter (ksteps == w mod 4)
  const int b = blockIdx.x;
  const int bg = b & 7;          // cluster: 8 batch groups x 16 rows; b%8 -> XCD if round-robin
  const int q = b >> 3;          // 0..31 within cluster
  const int layer = q & 1;
  const int colWG = q >> 1;      // 16 col groups x 32 cols

  char* ws = P.ws;
  u16* h0 = (u16*)(ws + H0_OFF);
  u16* h1 = (u16*)(ws + H1_OFF);
  u32* flags = (u32*)(ws + FLG_OFF) + bg * 64;   // 32 used per cluster
  u32* xslot = (u32*)(ws + XSL_OFF) + bg * 64;
  const bf16x8* px = (const bf16x8*)(ws + (layer ? PX1_OFF : PX0_OFF));
  const bf16x8* ph = (const bf16x8*)(ws + (layer ? PH1_OFF : PH0_OFF));

  const float* bih = layer ? P.bih1 : P.bih0;
  const float* bhh = layer ? P.bhh1 : P.bhh0;
  const int cw = w & 1;  // col-slice owned in gate phase (waves 0,1)
  const int jcol = colWG * 32 + cw * 16 + (lane & 15);
  const float b_r = bih[jcol] + bhh[jcol];
  const float b_z = bih[HDIM + jcol] + bhh[HDIM + jcol];
  const float b_nx = bih[2 * HDIM + jcol];
  const float b_nh = bhh[2 * HDIM + jcol];

  u16* hout = layer ? h1 : h0;
  const size_t bgoff = (size_t)bg * 16 * HDIM;

  // ---- persistent B fragments: col-slices sl = colWG*2 + cs; kstep = j*4 + w ----
  bf16x8 xB[3][2][4], hB[3][2][4];
#pragma unroll
  for (int ct = 0; ct < 3; ++ct)
#pragma unroll
    for (int cs = 0; cs < 2; ++cs)
#pragma unroll
      for (int j = 0; j < 4; ++j)
        hB[ct][cs][j] =
            ph[((size_t)((colWG * 2 + cs) * 3 + ct) * 16 + (j * 4 + w)) * 64 + lane];
  if (layer == 0) {
    const bf16x8 z8 = {0, 0, 0, 0, 0, 0, 0, 0};
#pragma unroll
    for (int ct = 0; ct < 3; ++ct)
#pragma unroll
      for (int cs = 0; cs < 2; ++cs)
#pragma unroll
        for (int j = 0; j < 4; ++j) xB[ct][cs][j] = z8;
    if (w < 2) {
#pragma unroll
      for (int ct = 0; ct < 3; ++ct)
#pragma unroll
        for (int cs = 0; cs < 2; ++cs)
          xB[ct][cs][0] = px[((size_t)((colWG * 2 + cs) * 3 + ct) * 2 + w) * 64 + lane];
    }
  } else {
#pragma unroll
    for (int ct = 0; ct < 3; ++ct)
#pragma unroll
      for (int cs = 0; cs < 2; ++cs)
#pragma unroll
        for (int j = 0; j < 4; ++j)
          xB[ct][cs][j] =
              px[((size_t)((colWG * 2 + cs) * 3 + ct) * 16 + (j * 4 + w)) * 64 + lane];
  }

  // ---- phase A: publish XCC_ID, verify cluster is XCD-local (G16-safe) ----
  u32 xcc = 0;
  asm volatile("s_getreg_b32 %0, hwreg(HW_REG_XCC_ID)" : "=s"(xcc));
  if (tid == 0) llc_st32(xslot + q, xcc + 1u);
  fast_barrier(flags, q, 1u);
  u32 mn = 0xFFFFFFFFu, mx = 0u;
  if (lane < 8) {
    uint4 v = llc_ld128(xslot + lane * 4);
    mn = umin2(umin2(v.x, v.y), umin2(v.z, v.w));
    mx = umax2(umax2(v.x, v.y), umax2(v.z, v.w));
  }
  mn = umin2(mn, __shfl_xor(mn, 1)); mx = umax2(mx, __shfl_xor(mx, 1));
  mn = umin2(mn, __shfl_xor(mn, 2)); mx = umax2(mx, __shfl_xor(mx, 2));
  mn = umin2(mn, __shfl_xor(mn, 4)); mx = umax2(mx, __shfl_xor(mx, 4));
  mn = __shfl(mn, 0); mx = __shfl(mx, 0);
  const bool isLocal = (mn != 0u) && (mn == mx);

  const f32x4 zf = {0.f, 0.f, 0.f, 0.f};
  f32x4 hown = zf;

#pragma unroll 1
  for (int tick = 0; tick <= TLEN; ++tick) {
    const int p = tick & 1;
    const bool active = (layer == 0) ? (tick < TLEN) : (tick >= 1);
    if (active) {
      f32x4 aR[2], aZ[2], aXN[2], aHN[2];
#pragma unroll
      for (int cs = 0; cs < 2; ++cs) { aR[cs] = zf; aZ[cs] = zf; aXN[cs] = zf; aHN[cs] = zf; }
      const u16* h0src = h0 + (size_t)(1 - p) * BATCH * HDIM + bgoff;

      if (layer == 0) {
        if (w < 2) {  // x-gemm (K=64), cached fp32 x
          const float* s = P.x +
              ((size_t)(bg * 16 + (lane & 15)) * TLEN + tick) * IDIM +
              w * 32 + ((lane >> 4) * 8);
          float4 v0 = ((const float4*)s)[0];
          float4 v1 = ((const float4*)s)[1];
          bf16x8 A;
          A[0] = (short)f2bf(v0.x); A[1] = (short)f2bf(v0.y);
          A[2] = (short)f2bf(v0.z); A[3] = (short)f2bf(v0.w);
          A[4] = (short)f2bf(v1.x); A[5] = (short)f2bf(v1.y);
          A[6] = (short)f2bf(v1.z); A[7] = (short)f2bf(v1.w);
#pragma unroll
          for (int cs = 0; cs < 2; ++cs) {
            aR[cs] = MFMA(A, xB[0][cs][0], aR[cs]);
            aZ[cs] = MFMA(A, xB[1][cs][0], aZ[cs]);
            aXN[cs] = MFMA(A, xB[2][cs][0], aXN[cs]);
          }
        }
        bf16x8 A[4];
        if (isLocal) {
#pragma unroll
          for (int j = 0; j < 4; ++j)
            l2_ldA(A[j], h0src + (size_t)(lane & 15) * HDIM + (j * 4 + w) * 32 +
                             ((lane >> 4) * 8));
        } else {
#pragma unroll
          for (int j = 0; j < 4; ++j)
            llc_ldA(A[j], h0src + (size_t)(lane & 15) * HDIM + (j * 4 + w) * 32 +
                              ((lane >> 4) * 8));
        }
        asm volatile("s_waitcnt vmcnt(0)" ::: "memory");
        __builtin_amdgcn_sched_barrier(0);
#pragma unroll
        for (int j = 0; j < 4; ++j)
#pragma unroll
          for (int cs = 0; cs < 2; ++cs) {
            aR[cs] = MFMA(A[j], hB[0][cs][j], aR[cs]);
            aZ[cs] = MFMA(A[j], hB[1][cs][j], aZ[cs]);
            aHN[cs] = MFMA(A[j], hB[2][cs][j], aHN[cs]);
          }
      } else {
        const u16* h1src = h1 + (size_t)(1 - p) * BATCH * HDIM + bgoff;
        bf16x8 A1[4], A2[4];
        if (isLocal) {
#pragma unroll
          for (int j = 0; j < 4; ++j) {
            const size_t off = (size_t)(lane & 15) * HDIM + (j * 4 + w) * 32 +
                               ((lane >> 4) * 8);
            l2_ldA(A1[j], h0src + off);
            l2_ldA(A2[j], h1src + off);
          }
        } else {
#pragma unroll
          for (int j = 0; j < 4; ++j) {
            const size_t off = (size_t)(lane & 15) * HDIM + (j * 4 + w) * 32 +
                               ((lane >> 4) * 8);
            llc_ldA(A1[j], h0src + off);
            llc_ldA(A2[j], h1src + off);
          }
        }
        asm volatile("s_waitcnt vmcnt(0)" ::: "memory");
        __builtin_amdgcn_sched_barrier(0);
#pragma unroll
        for (int j = 0; j < 4; ++j)
#pragma unroll
          for (int cs = 0; cs < 2; ++cs) {
            aR[cs] = MFMA(A1[j], xB[0][cs][j], aR[cs]);
            aZ[cs] = MFMA(A1[j], xB[1][cs][j], aZ[cs]);
            aXN[cs] = MFMA(A1[j], xB[2][cs][j], aXN[cs]);
          }
#pragma unroll
        for (int j = 0; j < 4; ++j)
#pragma unroll
          for (int cs = 0; cs < 2; ++cs) {
            aR[cs] = MFMA(A2[j], hB[0][cs][j], aR[cs]);
            aZ[cs] = MFMA(A2[j], hB[1][cs][j], aZ[cs]);
            aHN[cs] = MFMA(A2[j], hB[2][cs][j], aHN[cs]);
          }
      }

      // ---- cross-wave K reduction, 2 passes ----
#pragma unroll
      for (int cs = 0; cs < 2; ++cs) {
        red[w][0 + cs][lane] = aR[cs];
        red[w][2 + cs][lane] = aZ[cs];
      }
      __syncthreads();
      f32x4 R = zf, Z = zf, XN = zf, HN = zf;
#pragma unroll
      for (int kq = 0; kq < 4; ++kq) {
        R = R + red[kq][0 + cw][lane];
        Z = Z + red[kq][2 + cw][lane];
      }
      __syncthreads();
#pragma unroll
      for (int cs = 0; cs < 2; ++cs) {
        red[w][0 + cs][lane] = aXN[cs];
        red[w][2 + cs][lane] = aHN[cs];
      }
      __syncthreads();
#pragma unroll
      for (int kq = 0; kq < 4; ++kq) {
        XN = XN + red[kq][0 + cw][lane];
        HN = HN + red[kq][2 + cw][lane];
      }

      // ---- gates + state update + scoped h store (waves 0,1 own cs=0,1) ----
      if (w < 2) {
        u16* hw = hout + (size_t)p * BATCH * HDIM;
        u32 hv16[4];
        int rowb[4];
#pragma unroll
        for (int qq = 0; qq < 4; ++qq) {
          float r = sigm(R[qq] + b_r);
          float z = sigm(Z[qq] + b_z);
          float n = tanhfast(XN[qq] + b_nx + r * (HN[qq] + b_nh));
          float hv = (1.f - z) * n + z * hown[qq];
          hown[qq] = hv;
          hv16[qq] = (u32)f2bf(hv);
          rowb[qq] = bg * 16 + (lane >> 4) * 4 + qq;
        }
        if (isLocal) {
#pragma unroll
          for (int qq = 0; qq < 4; ++qq)
            l2_st16(&hw[(size_t)rowb[qq] * HDIM + jcol], hv16[qq]);
        } else {
#pragma unroll
          for (int qq = 0; qq < 4; ++qq)
            llc_st16(&hw[(size_t)rowb[qq] * HDIM + jcol], hv16[qq]);
        }
      }
    }
    fast_barrier(flags, q, (u32)(tick + 2));
  }

  // ---- final FC + sigmoid: hT1 = h1[parity 0] ----
  if (layer == 1 && colWG == 0) {
    const u16* hT = h1;  // p=0 holds t=999
    int row = tid >> 4, qq = tid & 15;
    const u16* hr = hT + (size_t)(bg * 16 + row) * HDIM + qq * 32;
    bf16x8 hv[4];
    if (isLocal) {
#pragma unroll
      for (int c = 0; c < 4; ++c) l2_ldA(hv[c], hr + c * 8);
    } else {
#pragma unroll
      for (int c = 0; c < 4; ++c) llc_ldA(hv[c], hr + c * 8);
    }
    asm volatile("s_waitcnt vmcnt(0)" ::: "memory");
    const float* wf = P.Wfc + qq * 32;
    float s = 0.f;
#pragma unroll
    for (int c = 0; c < 4; ++c)
#pragma unroll
      for (int k = 0; k < 8; ++k) s += bf2f((u16)hv[c][k]) * wf[c * 8 + k];
    s += __shfl_xor(s, 1);
    s += __shfl_xor(s, 2);
    s += __shfl_xor(s, 4);
    s += __shfl_xor(s, 8);
    if (qq == 0) P.out[bg * 16 + row] = sigm(s + P.bfc[0]);
  }
}

extern "C" void kernel_launch(void* const* d_in, const int* in_sizes, int n_in,
                              void* d_out, int out_size, void* d_ws, size_t ws_size,
                              hipStream_t stream) {
  const float* x = (const float*)d_in[0];
  const float* Wih0 = (const float*)d_in[1];
  const float* Whh0 = (const float*)d_in[2];
  const float* bih0 = (const float*)d_in[3];
  const float* bhh0 = (const float*)d_in[4];
  const float* Wih1 = (const float*)d_in[5];
  const float* Whh1 = (const float*)d_in[6];
  const float* bih1 = (const float*)d_in[7];
  const float* bhh1 = (const float*)d_in[8];
  const float* Wfc = (const float*)d_in[9];
  const float* bfc = (const float*)d_in[10];

  hipMemsetAsync(d_ws, 0, 524288, stream);                     // h double-buffers
  hipMemsetAsync((char*)d_ws + FLG_OFF, 0, 4096, stream);      // flags + xcc slots
  pack_weights<<<dim3(1200), dim3(NTHR), 0, stream>>>(Wih0, Whh0, Wih1, Whh1, (char*)d_ws);

  KP P = {x, bih0, bhh0, bih1, bhh1, Wfc, bfc, (float*)d_out, (char*)d_ws};
  void* args[] = {&P};
  hipError_t ce = hipLaunchCooperativeKernel((void*)gru_main, dim3(NWG), dim3(NTHR), args, 0,
                                             stream);
  if (ce != hipSuccess) {
    // 256 WGs x 4 waves: 1 wave/SIMD minimum -> always fully co-resident on 256 CUs;
    // barrier is hand-rolled flags, so a plain launch is safe.
    (void)hipGetLastError();  // clear error state
    gru_main<<<dim3(NWG), dim3(NTHR), 0, stream>>>(P);
  }
}